// Round 1
// baseline (505.254 us; speedup 1.0000x reference)
//
#include <hip/hip_runtime.h>
#include <hip/hip_bf16.h>

// GCN 2-layer forward on MI355X (gfx950). fp32 in/out, int32 edges.
// Round 6: k_fill was writeback-amplification-bound (105MB WRITE_SIZE for a
// 6.4MB ebuf; 0.91 TB/s scattered-line ceiling). Replaced the whole CSR build
// (count_deg + 3 scans + fill, ~160us) with a two-level bucket sort:
//   binA: bin edges by dst>>9 into 196 buckets, LDS histogram + run
//         reservation -> coalesced packed writes ((dstlow<<17)|src).
//   bucketscan: tiny exclusive scan of bucket totals.
//   binB: one block per bucket: LDS histogram (=degree) -> rowptr+dinv,
//         then scatter src ids within a ~32KB L2-resident window.
// Gather/GEMM kernels unchanged from round 5.
// Round 7: resubmission of round-6 source unchanged (bench infra failed; no
// counters to act on). Baseline re-measure.

typedef __attribute__((ext_vector_type(8))) short bf16x8;   // 8 bf16 = 4 VGPRs
typedef __attribute__((ext_vector_type(4))) float f32x4;    // MFMA C/D

constexpr int NN = 100000;   // nodes
constexpr int NF = 512;      // input feats
constexpr int NH = 64;       // hidden
constexpr int NC = 40;       // classes
constexpr int NE = 1600000;  // edges

constexpr int NBUCK = 196;     // ceil(NN/512): bucket = dst >> 9
constexpr int CAP   = 12288;   // staging capacity/bucket (mean 8163, +45 sigma)
constexpr int ABLK  = 256;     // binA blocks
constexpr int CHUNK = NE / ABLK;  // 6250 edges/block (exact)

// ---- ws layout (byte offsets) ----
constexpr size_t OFF_DINV   = 0;           // float[NN]
constexpr size_t OFF_ROWPTR = 524288;      // int[NN+1]
constexpr size_t OFF_GCUR   = 1048576;     // int[256] bucket cursors/totals
constexpr size_t OFF_GOFS   = 1049600;     // int[256] bucket base offsets
constexpr size_t OFF_W1BF   = 1576960;     // bf16[64*512] = 64KB
constexpr size_t OFF_W2BF   = 1642496;     // bf16[40*64]
constexpr size_t OFF_EBUF   = 2097152;     // int[NE] CSR src ids, 6.4MB
constexpr size_t OFF_H1     = 9437184;     // bf16[NN*64] = 12.8MB (h2s reuses)
constexpr size_t OFF_R1     = 23068672;    // bf16[NN*64] = 12.8MB
// staging int[NBUCK*CAP] = 9.63MB ALIASES h1s/r1 region (dead during CSR build)
constexpr size_t OFF_STAGE  = OFF_H1;

// fp32 -> bf16 fragment helpers
__device__ inline short f2bs(float f) {
    union { __hip_bfloat16 h; short s; } u;
    u.h = __float2bfloat16(f);
    return u.s;
}
__device__ inline bf16x8 cvt8(const float* __restrict__ p) {
    bf16x8 r;
#pragma unroll
    for (int i = 0; i < 8; ++i) r[i] = f2bs(p[i]);
    return r;
}

// ---------------- W1/W2 fp32 -> bf16 (once) + zero bucket cursors ----------
__global__ __launch_bounds__(256) void k_cvtw(const float* __restrict__ W1,
                                              const float* __restrict__ W2,
                                              __hip_bfloat16* __restrict__ W1bf,
                                              __hip_bfloat16* __restrict__ W2bf,
                                              int* __restrict__ gcur) {
    int i = blockIdx.x * 256 + threadIdx.x;
    if (i < NH * NF) W1bf[i] = __float2bfloat16(W1[i]);
    int j = i - NH * NF;
    if (j >= 0 && j < NC * NH) W2bf[j] = __float2bfloat16(W2[j]);
    if (i < 256) gcur[i] = 0;
}

// ---------------- binA: bucket edges by dst>>9, coalesced packed writes ----
__global__ __launch_bounds__(256) void k_binA(const int* __restrict__ src,
                                              const int* __restrict__ dst,
                                              int* __restrict__ gcur,
                                              int* __restrict__ staging) {
    __shared__ int cnt[NBUCK];
    __shared__ int base[NBUCK];
    __shared__ int cur[NBUCK];
    const int t = threadIdx.x;
    const int e0 = blockIdx.x * CHUNK;
    for (int i = t; i < NBUCK; i += 256) { cnt[i] = 0; cur[i] = 0; }
    __syncthreads();
    for (int i = t; i < CHUNK; i += 256)
        atomicAdd(&cnt[dst[e0 + i] >> 9], 1);
    __syncthreads();
    for (int i = t; i < NBUCK; i += 256)
        base[i] = atomicAdd(&gcur[i], cnt[i]);   // reserve contiguous run
    __syncthreads();
    for (int i = t; i < CHUNK; i += 256) {
        int e = e0 + i;
        int d = dst[e];
        int b = d >> 9;
        int r = atomicAdd(&cur[b], 1);
        int pos = base[b] + r;
        if (pos < CAP)                            // deterministic input: never trips
            staging[b * CAP + pos] = ((d & 511) << 17) | src[e];
    }
}

// ---------------- exclusive scan of bucket totals -> gofs ----------------
__global__ __launch_bounds__(256) void k_bucketscan(const int* __restrict__ gcur,
                                                    int* __restrict__ gofs,
                                                    int* __restrict__ rowptr) {
    __shared__ int s[256];
    int t = threadIdx.x;
    int v = (t < NBUCK) ? gcur[t] : 0;
    s[t] = v;
    __syncthreads();
    for (int off = 1; off < 256; off <<= 1) {
        int tv = (t >= off) ? s[t - off] : 0;
        __syncthreads();
        s[t] += tv;
        __syncthreads();
    }
    if (t < NBUCK) gofs[t] = s[t] - v;   // exclusive
    if (t == 0) rowptr[NN] = NE;
}

// ---------------- binB: per-bucket degree/rowptr/dinv + local CSR scatter ----
__global__ __launch_bounds__(512) void k_binB(const int* __restrict__ gcur,
                                              const int* __restrict__ gofs,
                                              const int* __restrict__ staging,
                                              int* __restrict__ rowptr,
                                              float* __restrict__ dinv,
                                              int* __restrict__ ebuf) {
    __shared__ int hist[512];
    __shared__ int s[512];
    __shared__ int cur[512];
    const int b = blockIdx.x, t = threadIdx.x;
    const int count = gcur[b];
    const int sbase = b * CAP;
    hist[t] = 0;
    __syncthreads();
    for (int i = t; i < count; i += 512)
        atomicAdd(&hist[staging[sbase + i] >> 17], 1);
    __syncthreads();
    int v = hist[t];
    s[t] = v;
    __syncthreads();
    for (int off = 1; off < 512; off <<= 1) {
        int tv = (t >= off) ? s[t - off] : 0;
        __syncthreads();
        s[t] += tv;
        __syncthreads();
    }
    const int excl = s[t] - v;           // local exclusive offset
    const int base = gofs[b];
    int n = b * 512 + t;
    if (n < NN) {
        rowptr[n] = base + excl;
        dinv[n] = rsqrtf((float)v + 1.0f);   // +1 = self-loop
    }
    cur[t] = excl;
    __syncthreads();
    for (int i = t; i < count; i += 512) {
        int pv = staging[sbase + i];
        int p = atomicAdd(&cur[pv >> 17], 1);
        ebuf[base + p] = pv & 0x1FFFF;   // src id
    }
}

// ---------------- GEMM1: h1s[NN,64] = (x @ W1^T) * dinv[row]  (bf16) ----
__global__ __launch_bounds__(256) void k_gemm1(const float* __restrict__ x,
                                               const __hip_bfloat16* __restrict__ W1bf,
                                               const float* __restrict__ dinv,
                                               __hip_bfloat16* __restrict__ h1s) {
    const int lane = threadIdx.x & 63;
    const int wave = blockIdx.x * 4 + (threadIdx.x >> 6);
    const int row0 = wave * 64;
    if (row0 >= NN) return;
    const int q = lane >> 4, m = lane & 15;

    f32x4 acc[4][4];
#pragma unroll
    for (int i = 0; i < 4; ++i)
#pragma unroll
        for (int j = 0; j < 4; ++j) acc[i][j] = (f32x4){0.f, 0.f, 0.f, 0.f};

    for (int k0 = 0; k0 < NF; k0 += 32) {
        bf16x8 bfr[4];
#pragma unroll
        for (int ot = 0; ot < 4; ++ot)
            bfr[ot] = *reinterpret_cast<const bf16x8*>(W1bf + (ot * 16 + m) * NF + k0 + q * 8);
#pragma unroll
        for (int mt = 0; mt < 4; ++mt) {
            int r = row0 + mt * 16 + m;
            if (r > NN - 1) r = NN - 1;  // tail clamp (store guarded)
            bf16x8 afr = cvt8(x + (size_t)r * NF + k0 + q * 8);
#pragma unroll
            for (int ot = 0; ot < 4; ++ot)
                acc[mt][ot] = __builtin_amdgcn_mfma_f32_16x16x32_bf16(afr, bfr[ot], acc[mt][ot], 0, 0, 0);
        }
    }

#pragma unroll
    for (int mt = 0; mt < 4; ++mt)
#pragma unroll
        for (int rr = 0; rr < 4; ++rr) {
            int row = row0 + mt * 16 + q * 4 + rr;
            if (row < NN) {
                float di = dinv[row];
#pragma unroll
                for (int ot = 0; ot < 4; ++ot)
                    h1s[row * NH + ot * 16 + m] = __float2bfloat16(acc[mt][ot][rr] * di);
            }
        }
}

// ---------------- gather1: r1[n] = relu(dn * (sum h1s[s] + h1s[n]) + b1) ----
__global__ __launch_bounds__(256) void k_gather1(const int* __restrict__ rowptr,
                                                 const int* __restrict__ ebuf,
                                                 const float* __restrict__ dinv,
                                                 const __hip_bfloat16* __restrict__ h1s,
                                                 const float* __restrict__ b1,
                                                 __hip_bfloat16* __restrict__ r1) {
    const int lane = threadIdx.x & 63;
    const int n = blockIdx.x * 4 + (threadIdx.x >> 6);
    if (n >= NN) return;
    const int beg = rowptr[n], end = rowptr[n + 1];
    float acc = 0.0f;
    int j = beg;
    for (; j + 8 <= end; j += 8) {
        int e0 = ebuf[j + 0], e1 = ebuf[j + 1], e2 = ebuf[j + 2], e3 = ebuf[j + 3];
        int e4 = ebuf[j + 4], e5 = ebuf[j + 5], e6 = ebuf[j + 6], e7 = ebuf[j + 7];
        float v0 = __bfloat162float(h1s[e0 * NH + lane]);
        float v1 = __bfloat162float(h1s[e1 * NH + lane]);
        float v2 = __bfloat162float(h1s[e2 * NH + lane]);
        float v3 = __bfloat162float(h1s[e3 * NH + lane]);
        float v4 = __bfloat162float(h1s[e4 * NH + lane]);
        float v5 = __bfloat162float(h1s[e5 * NH + lane]);
        float v6 = __bfloat162float(h1s[e6 * NH + lane]);
        float v7 = __bfloat162float(h1s[e7 * NH + lane]);
        acc += ((v0 + v1) + (v2 + v3)) + ((v4 + v5) + (v6 + v7));
    }
    for (; j < end; ++j)
        acc += __bfloat162float(h1s[ebuf[j] * NH + lane]);
    acc += __bfloat162float(h1s[n * NH + lane]);   // self-loop (pre-scaled)
    acc = acc * dinv[n] + b1[lane];
    r1[n * NH + lane] = __float2bfloat16(fmaxf(acc, 0.0f));
}

// ---------------- GEMM2: h2s[NN,40] = (r1 @ W2^T) * dinv[row]  (bf16) ----
__global__ __launch_bounds__(256) void k_gemm2(const __hip_bfloat16* __restrict__ r1,
                                               const __hip_bfloat16* __restrict__ W2bf,
                                               const float* __restrict__ dinv,
                                               __hip_bfloat16* __restrict__ h2s) {
    const int lane = threadIdx.x & 63;
    const int wave = blockIdx.x * 4 + (threadIdx.x >> 6);
    const int row0 = wave * 64;
    if (row0 >= NN) return;
    const int q = lane >> 4, m = lane & 15;

    f32x4 acc[4][3];
#pragma unroll
    for (int i = 0; i < 4; ++i)
#pragma unroll
        for (int j = 0; j < 3; ++j) acc[i][j] = (f32x4){0.f, 0.f, 0.f, 0.f};

#pragma unroll
    for (int k0 = 0; k0 < NH; k0 += 32) {
        bf16x8 bfr[3];
#pragma unroll
        for (int ot = 0; ot < 3; ++ot) {
            int o = ot * 16 + m;
            if (o > NC - 1) o = NC - 1;  // stay inside W2's 40 rows
            bfr[ot] = *reinterpret_cast<const bf16x8*>(W2bf + o * NH + k0 + q * 8);
        }
#pragma unroll
        for (int mt = 0; mt < 4; ++mt) {
            int r = row0 + mt * 16 + m;
            if (r > NN - 1) r = NN - 1;
            bf16x8 afr = *reinterpret_cast<const bf16x8*>(r1 + r * NH + k0 + q * 8);
#pragma unroll
            for (int ot = 0; ot < 3; ++ot)
                acc[mt][ot] = __builtin_amdgcn_mfma_f32_16x16x32_bf16(afr, bfr[ot], acc[mt][ot], 0, 0, 0);
        }
    }

#pragma unroll
    for (int mt = 0; mt < 4; ++mt)
#pragma unroll
        for (int rr = 0; rr < 4; ++rr) {
            int row = row0 + mt * 16 + q * 4 + rr;
            if (row < NN) {
                float di = dinv[row];
#pragma unroll
                for (int ot = 0; ot < 3; ++ot) {
                    int col = ot * 16 + m;
                    if (col < NC) h2s[row * NC + col] = __float2bfloat16(acc[mt][ot][rr] * di);
                }
            }
        }
}

// ---------------- gather2: out[n] = dn*(sum h2s[s] + h2s[n]) + b2 (fp32) ----
__global__ __launch_bounds__(256) void k_gather2(const int* __restrict__ rowptr,
                                                 const int* __restrict__ ebuf,
                                                 const float* __restrict__ dinv,
                                                 const __hip_bfloat16* __restrict__ h2s,
                                                 const float* __restrict__ b2,
                                                 float* __restrict__ out) {
    const int lane = threadIdx.x & 63;
    const int n = blockIdx.x * 4 + (threadIdx.x >> 6);
    if (n >= NN || lane >= NC) return;
    const int beg = rowptr[n], end = rowptr[n + 1];
    float acc = 0.0f;
    int j = beg;
    for (; j + 8 <= end; j += 8) {
        int e0 = ebuf[j + 0], e1 = ebuf[j + 1], e2 = ebuf[j + 2], e3 = ebuf[j + 3];
        int e4 = ebuf[j + 4], e5 = ebuf[j + 5], e6 = ebuf[j + 6], e7 = ebuf[j + 7];
        float v0 = __bfloat162float(h2s[e0 * NC + lane]);
        float v1 = __bfloat162float(h2s[e1 * NC + lane]);
        float v2 = __bfloat162float(h2s[e2 * NC + lane]);
        float v3 = __bfloat162float(h2s[e3 * NC + lane]);
        float v4 = __bfloat162float(h2s[e4 * NC + lane]);
        float v5 = __bfloat162float(h2s[e5 * NC + lane]);
        float v6 = __bfloat162float(h2s[e6 * NC + lane]);
        float v7 = __bfloat162float(h2s[e7 * NC + lane]);
        acc += ((v0 + v1) + (v2 + v3)) + ((v4 + v5) + (v6 + v7));
    }
    for (; j < end; ++j)
        acc += __bfloat162float(h2s[ebuf[j] * NC + lane]);
    acc += __bfloat162float(h2s[n * NC + lane]);   // self-loop (pre-scaled)
    out[n * NC + lane] = acc * dinv[n] + b2[lane];
}

extern "C" void kernel_launch(void* const* d_in, const int* in_sizes, int n_in,
                              void* d_out, int out_size, void* d_ws, size_t ws_size,
                              hipStream_t stream) {
    const float* x  = (const float*)d_in[0];
    const int*   ei = (const int*)d_in[1];
    const float* W1 = (const float*)d_in[2];
    const float* b1 = (const float*)d_in[3];
    const float* W2 = (const float*)d_in[4];
    const float* b2 = (const float*)d_in[5];
    const int* srcp = ei;        // edge_index[0]
    const int* dstp = ei + NE;   // edge_index[1]

    char* ws = (char*)d_ws;
    float*          dinv    = (float*)(ws + OFF_DINV);
    int*            rowptr  = (int*)(ws + OFF_ROWPTR);
    int*            gcur    = (int*)(ws + OFF_GCUR);
    int*            gofs    = (int*)(ws + OFF_GOFS);
    __hip_bfloat16* W1bf    = (__hip_bfloat16*)(ws + OFF_W1BF);
    __hip_bfloat16* W2bf    = (__hip_bfloat16*)(ws + OFF_W2BF);
    int*            ebuf    = (int*)(ws + OFF_EBUF);
    int*            staging = (int*)(ws + OFF_STAGE);          // aliases h1s/r1
    __hip_bfloat16* h1s     = (__hip_bfloat16*)(ws + OFF_H1);  // h2s reuses
    __hip_bfloat16* r1      = (__hip_bfloat16*)(ws + OFF_R1);

    // --- weights to bf16 + zero bucket cursors ---
    k_cvtw<<<(NH * NF + NC * NH + 255) / 256, 256, 0, stream>>>(W1, W2, W1bf, W2bf, gcur);

    // --- CSR build: two-level bucket sort (staging aliases h1s/r1, dead here) ---
    k_binA<<<ABLK, 256, 0, stream>>>(srcp, dstp, gcur, staging);
    k_bucketscan<<<1, 256, 0, stream>>>(gcur, gofs, rowptr);
    k_binB<<<NBUCK, 512, 0, stream>>>(gcur, gofs, staging, rowptr, dinv, ebuf);

    const int gemm_blocks = (NN + 255) / 256;   // 4 waves/block, 64 rows/wave
    const int node_blocks = (NN + 3) / 4;       // 4 waves/block, 1 node/wave

    // --- layer 1 ---
    k_gemm1<<<gemm_blocks, 256, 0, stream>>>(x, W1bf, dinv, h1s);
    k_gather1<<<node_blocks, 256, 0, stream>>>(rowptr, ebuf, dinv, h1s, b1, r1);

    // --- layer 2 (h2s reuses h1s's buffer) ---
    __hip_bfloat16* h2s = h1s;
    k_gemm2<<<gemm_blocks, 256, 0, stream>>>(r1, W2bf, dinv, h2s);
    k_gather2<<<node_blocks, 256, 0, stream>>>(rowptr, ebuf, dinv, h2s, b2,
                                               (float*)d_out);
}

// Round 2
// 499.144 us; speedup vs baseline: 1.0122x; 1.0122x over previous
//
#include <hip/hip_runtime.h>
#include <hip/hip_bf16.h>

// GCN 2-layer forward on MI355X (gfx950). fp32 in/out, int32 edges.
// Round 7 (505.25us baseline confirmed; all kernels <119us, top-5 = harness fills):
//   1. h2s padded to stride 64 (128B line-aligned rows): gather2 was fetching
//      1.5 lines/edge (80B rows straddling 128B lines) -> now exactly 1.
//   2. CSR bucket sort rebalanced: 256-node buckets (NBUCK=391), binB blocks
//      of 256 threads -> ~2x block count for occupancy + better tail balance.
//   3. k_bucketscan fused into binB (per-block tree-reduce of gcur prefix).
// Gather1/GEMM1 unchanged (gather1 already 1 aligned line/edge; gemm1 at the
// 204.8MB fp32 x-read HBM floor ~40us).

typedef __attribute__((ext_vector_type(8))) short bf16x8;   // 8 bf16 = 4 VGPRs
typedef __attribute__((ext_vector_type(4))) float f32x4;    // MFMA C/D

constexpr int NN = 100000;   // nodes
constexpr int NF = 512;      // input feats
constexpr int NH = 64;       // hidden
constexpr int NC = 40;       // classes
constexpr int NE = 1600000;  // edges

constexpr int NBUCK = 391;     // ceil(NN/256): bucket = dst >> 8
constexpr int CAP   = 6144;    // staging capacity/bucket (mean 4092, +32 sigma)
constexpr int ABLK  = 256;     // binA blocks
constexpr int CHUNK = NE / ABLK;  // 6250 edges/block (exact)

// ---- ws layout (byte offsets) ----
constexpr size_t OFF_DINV   = 0;           // float[NN]
constexpr size_t OFF_ROWPTR = 524288;      // int[NN+1]
constexpr size_t OFF_GCUR   = 1048576;     // int[512] bucket totals (391 used)
constexpr size_t OFF_W1BF   = 1576960;     // bf16[64*512] = 64KB
constexpr size_t OFF_W2BF   = 1642496;     // bf16[40*64]
constexpr size_t OFF_EBUF   = 2097152;     // int[NE] CSR src ids, 6.4MB
constexpr size_t OFF_H1     = 9437184;     // bf16[NN*64] = 12.8MB (h2s reuses, padded)
constexpr size_t OFF_R1     = 23068672;    // bf16[NN*64] = 12.8MB
// staging int[NBUCK*CAP] = 9.61MB ALIASES h1s region (dead during CSR build)
constexpr size_t OFF_STAGE  = OFF_H1;

// fp32 -> bf16 fragment helpers
__device__ inline short f2bs(float f) {
    union { __hip_bfloat16 h; short s; } u;
    u.h = __float2bfloat16(f);
    return u.s;
}
__device__ inline bf16x8 cvt8(const float* __restrict__ p) {
    bf16x8 r;
#pragma unroll
    for (int i = 0; i < 8; ++i) r[i] = f2bs(p[i]);
    return r;
}

// ---------------- W1/W2 fp32 -> bf16 (once) + zero bucket cursors ----------
__global__ __launch_bounds__(256) void k_cvtw(const float* __restrict__ W1,
                                              const float* __restrict__ W2,
                                              __hip_bfloat16* __restrict__ W1bf,
                                              __hip_bfloat16* __restrict__ W2bf,
                                              int* __restrict__ gcur) {
    int i = blockIdx.x * 256 + threadIdx.x;
    if (i < NH * NF) W1bf[i] = __float2bfloat16(W1[i]);
    int j = i - NH * NF;
    if (j >= 0 && j < NC * NH) W2bf[j] = __float2bfloat16(W2[j]);
    if (i < 512) gcur[i] = 0;
}

// ---------------- binA: bucket edges by dst>>8, coalesced packed writes ----
__global__ __launch_bounds__(256) void k_binA(const int* __restrict__ src,
                                              const int* __restrict__ dst,
                                              int* __restrict__ gcur,
                                              int* __restrict__ staging) {
    __shared__ int cnt[NBUCK];
    __shared__ int base[NBUCK];
    __shared__ int cur[NBUCK];
    const int t = threadIdx.x;
    const int e0 = blockIdx.x * CHUNK;
    for (int i = t; i < NBUCK; i += 256) { cnt[i] = 0; cur[i] = 0; }
    __syncthreads();
    for (int i = t; i < CHUNK; i += 256)
        atomicAdd(&cnt[dst[e0 + i] >> 8], 1);
    __syncthreads();
    for (int i = t; i < NBUCK; i += 256)
        base[i] = atomicAdd(&gcur[i], cnt[i]);   // reserve contiguous run
    __syncthreads();
    for (int i = t; i < CHUNK; i += 256) {
        int e = e0 + i;
        int d = dst[e];
        int b = d >> 8;
        int r = atomicAdd(&cur[b], 1);
        int pos = base[b] + r;
        if (pos < CAP)                            // deterministic input: never trips
            staging[b * CAP + pos] = ((d & 255) << 17) | src[e];
    }
}

// ---------------- binB: per-bucket prefix + degree/rowptr/dinv + CSR scatter ----
__global__ __launch_bounds__(256) void k_binB(const int* __restrict__ gcur,
                                              const int* __restrict__ staging,
                                              int* __restrict__ rowptr,
                                              float* __restrict__ dinv,
                                              int* __restrict__ ebuf) {
    __shared__ int redbuf[256];
    __shared__ int hist[256];
    __shared__ int s[256];
    __shared__ int cur[256];
    const int b = blockIdx.x, t = threadIdx.x;
    const int count = gcur[b];
    const int sbase = b * CAP;

    // fused exclusive-prefix: base = sum(gcur[0..b))
    int acc0 = 0;
    if (t < b) acc0 = gcur[t];
    if (t + 256 < b) acc0 += gcur[t + 256];
    redbuf[t] = acc0;
    hist[t] = 0;
    __syncthreads();
    for (int off = 128; off > 0; off >>= 1) {
        if (t < off) redbuf[t] += redbuf[t + off];
        __syncthreads();
    }
    const int base = redbuf[0];

    // in-bucket histogram (= per-node degree)
    for (int i = t; i < count; i += 256)
        atomicAdd(&hist[staging[sbase + i] >> 17], 1);
    __syncthreads();
    int v = hist[t];
    s[t] = v;
    __syncthreads();
    for (int off = 1; off < 256; off <<= 1) {
        int tv = (t >= off) ? s[t - off] : 0;
        __syncthreads();
        s[t] += tv;
        __syncthreads();
    }
    const int excl = s[t] - v;           // local exclusive offset
    int n = b * 256 + t;
    if (n < NN) {
        rowptr[n] = base + excl;
        dinv[n] = rsqrtf((float)v + 1.0f);   // +1 = self-loop
    }
    if (b == 0 && t == 0) rowptr[NN] = NE;
    cur[t] = excl;
    __syncthreads();
    for (int i = t; i < count; i += 256) {
        int pv = staging[sbase + i];
        int p = atomicAdd(&cur[pv >> 17], 1);
        ebuf[base + p] = pv & 0x1FFFF;   // src id
    }
}

// ---------------- GEMM1: h1s[NN,64] = (x @ W1^T) * dinv[row]  (bf16) ----
__global__ __launch_bounds__(256) void k_gemm1(const float* __restrict__ x,
                                               const __hip_bfloat16* __restrict__ W1bf,
                                               const float* __restrict__ dinv,
                                               __hip_bfloat16* __restrict__ h1s) {
    const int lane = threadIdx.x & 63;
    const int wave = blockIdx.x * 4 + (threadIdx.x >> 6);
    const int row0 = wave * 64;
    if (row0 >= NN) return;
    const int q = lane >> 4, m = lane & 15;

    f32x4 acc[4][4];
#pragma unroll
    for (int i = 0; i < 4; ++i)
#pragma unroll
        for (int j = 0; j < 4; ++j) acc[i][j] = (f32x4){0.f, 0.f, 0.f, 0.f};

    for (int k0 = 0; k0 < NF; k0 += 32) {
        bf16x8 bfr[4];
#pragma unroll
        for (int ot = 0; ot < 4; ++ot)
            bfr[ot] = *reinterpret_cast<const bf16x8*>(W1bf + (ot * 16 + m) * NF + k0 + q * 8);
#pragma unroll
        for (int mt = 0; mt < 4; ++mt) {
            int r = row0 + mt * 16 + m;
            if (r > NN - 1) r = NN - 1;  // tail clamp (store guarded)
            bf16x8 afr = cvt8(x + (size_t)r * NF + k0 + q * 8);
#pragma unroll
            for (int ot = 0; ot < 4; ++ot)
                acc[mt][ot] = __builtin_amdgcn_mfma_f32_16x16x32_bf16(afr, bfr[ot], acc[mt][ot], 0, 0, 0);
        }
    }

#pragma unroll
    for (int mt = 0; mt < 4; ++mt)
#pragma unroll
        for (int rr = 0; rr < 4; ++rr) {
            int row = row0 + mt * 16 + q * 4 + rr;
            if (row < NN) {
                float di = dinv[row];
#pragma unroll
                for (int ot = 0; ot < 4; ++ot)
                    h1s[row * NH + ot * 16 + m] = __float2bfloat16(acc[mt][ot][rr] * di);
            }
        }
}

// ---------------- gather1: r1[n] = relu(dn * (sum h1s[s] + h1s[n]) + b1) ----
__global__ __launch_bounds__(256) void k_gather1(const int* __restrict__ rowptr,
                                                 const int* __restrict__ ebuf,
                                                 const float* __restrict__ dinv,
                                                 const __hip_bfloat16* __restrict__ h1s,
                                                 const float* __restrict__ b1,
                                                 __hip_bfloat16* __restrict__ r1) {
    const int lane = threadIdx.x & 63;
    const int n = blockIdx.x * 4 + (threadIdx.x >> 6);
    if (n >= NN) return;
    const int beg = rowptr[n], end = rowptr[n + 1];
    // independent loads issued early: self-loop row + bias + dinv
    float selfv = __bfloat162float(h1s[n * NH + lane]);
    float bias = b1[lane];
    float dn = dinv[n];
    float acc = 0.0f;
    int j = beg;
    for (; j + 8 <= end; j += 8) {
        int e0 = ebuf[j + 0], e1 = ebuf[j + 1], e2 = ebuf[j + 2], e3 = ebuf[j + 3];
        int e4 = ebuf[j + 4], e5 = ebuf[j + 5], e6 = ebuf[j + 6], e7 = ebuf[j + 7];
        float v0 = __bfloat162float(h1s[e0 * NH + lane]);
        float v1 = __bfloat162float(h1s[e1 * NH + lane]);
        float v2 = __bfloat162float(h1s[e2 * NH + lane]);
        float v3 = __bfloat162float(h1s[e3 * NH + lane]);
        float v4 = __bfloat162float(h1s[e4 * NH + lane]);
        float v5 = __bfloat162float(h1s[e5 * NH + lane]);
        float v6 = __bfloat162float(h1s[e6 * NH + lane]);
        float v7 = __bfloat162float(h1s[e7 * NH + lane]);
        acc += ((v0 + v1) + (v2 + v3)) + ((v4 + v5) + (v6 + v7));
    }
    for (; j < end; ++j)
        acc += __bfloat162float(h1s[ebuf[j] * NH + lane]);
    acc += selfv;   // self-loop (pre-scaled)
    acc = acc * dn + bias;
    r1[n * NH + lane] = __float2bfloat16(fmaxf(acc, 0.0f));
}

// ---------------- GEMM2: h2s[NN,64pad] = (r1 @ W2^T) * dinv[row]  (bf16) ----
__global__ __launch_bounds__(256) void k_gemm2(const __hip_bfloat16* __restrict__ r1,
                                               const __hip_bfloat16* __restrict__ W2bf,
                                               const float* __restrict__ dinv,
                                               __hip_bfloat16* __restrict__ h2s) {
    const int lane = threadIdx.x & 63;
    const int wave = blockIdx.x * 4 + (threadIdx.x >> 6);
    const int row0 = wave * 64;
    if (row0 >= NN) return;
    const int q = lane >> 4, m = lane & 15;

    f32x4 acc[4][3];
#pragma unroll
    for (int i = 0; i < 4; ++i)
#pragma unroll
        for (int j = 0; j < 3; ++j) acc[i][j] = (f32x4){0.f, 0.f, 0.f, 0.f};

#pragma unroll
    for (int k0 = 0; k0 < NH; k0 += 32) {
        bf16x8 bfr[3];
#pragma unroll
        for (int ot = 0; ot < 3; ++ot) {
            int o = ot * 16 + m;
            if (o > NC - 1) o = NC - 1;  // stay inside W2's 40 rows
            bfr[ot] = *reinterpret_cast<const bf16x8*>(W2bf + o * NH + k0 + q * 8);
        }
#pragma unroll
        for (int mt = 0; mt < 4; ++mt) {
            int r = row0 + mt * 16 + m;
            if (r > NN - 1) r = NN - 1;
            bf16x8 afr = *reinterpret_cast<const bf16x8*>(r1 + r * NH + k0 + q * 8);
#pragma unroll
            for (int ot = 0; ot < 3; ++ot)
                acc[mt][ot] = __builtin_amdgcn_mfma_f32_16x16x32_bf16(afr, bfr[ot], acc[mt][ot], 0, 0, 0);
        }
    }

#pragma unroll
    for (int mt = 0; mt < 4; ++mt)
#pragma unroll
        for (int rr = 0; rr < 4; ++rr) {
            int row = row0 + mt * 16 + q * 4 + rr;
            if (row < NN) {
                float di = dinv[row];
#pragma unroll
                for (int ot = 0; ot < 3; ++ot) {
                    int col = ot * 16 + m;
                    if (col < NC) h2s[row * 64 + col] = __float2bfloat16(acc[mt][ot][rr] * di);
                }
            }
        }
}

// ---------------- gather2: out[n] = dn*(sum h2s[s] + h2s[n]) + b2 (fp32) ----
__global__ __launch_bounds__(256) void k_gather2(const int* __restrict__ rowptr,
                                                 const int* __restrict__ ebuf,
                                                 const float* __restrict__ dinv,
                                                 const __hip_bfloat16* __restrict__ h2s,
                                                 const float* __restrict__ b2,
                                                 float* __restrict__ out) {
    const int lane = threadIdx.x & 63;
    const int n = blockIdx.x * 4 + (threadIdx.x >> 6);
    if (n >= NN || lane >= NC) return;
    const int beg = rowptr[n], end = rowptr[n + 1];
    float selfv = __bfloat162float(h2s[n * 64 + lane]);
    float bias = b2[lane];
    float dn = dinv[n];
    float acc = 0.0f;
    int j = beg;
    for (; j + 8 <= end; j += 8) {
        int e0 = ebuf[j + 0], e1 = ebuf[j + 1], e2 = ebuf[j + 2], e3 = ebuf[j + 3];
        int e4 = ebuf[j + 4], e5 = ebuf[j + 5], e6 = ebuf[j + 6], e7 = ebuf[j + 7];
        float v0 = __bfloat162float(h2s[e0 * 64 + lane]);
        float v1 = __bfloat162float(h2s[e1 * 64 + lane]);
        float v2 = __bfloat162float(h2s[e2 * 64 + lane]);
        float v3 = __bfloat162float(h2s[e3 * 64 + lane]);
        float v4 = __bfloat162float(h2s[e4 * 64 + lane]);
        float v5 = __bfloat162float(h2s[e5 * 64 + lane]);
        float v6 = __bfloat162float(h2s[e6 * 64 + lane]);
        float v7 = __bfloat162float(h2s[e7 * 64 + lane]);
        acc += ((v0 + v1) + (v2 + v3)) + ((v4 + v5) + (v6 + v7));
    }
    for (; j < end; ++j)
        acc += __bfloat162float(h2s[ebuf[j] * 64 + lane]);
    acc += selfv;   // self-loop (pre-scaled)
    out[n * NC + lane] = acc * dn + bias;
}

extern "C" void kernel_launch(void* const* d_in, const int* in_sizes, int n_in,
                              void* d_out, int out_size, void* d_ws, size_t ws_size,
                              hipStream_t stream) {
    const float* x  = (const float*)d_in[0];
    const int*   ei = (const int*)d_in[1];
    const float* W1 = (const float*)d_in[2];
    const float* b1 = (const float*)d_in[3];
    const float* W2 = (const float*)d_in[4];
    const float* b2 = (const float*)d_in[5];
    const int* srcp = ei;        // edge_index[0]
    const int* dstp = ei + NE;   // edge_index[1]

    char* ws = (char*)d_ws;
    float*          dinv    = (float*)(ws + OFF_DINV);
    int*            rowptr  = (int*)(ws + OFF_ROWPTR);
    int*            gcur    = (int*)(ws + OFF_GCUR);
    __hip_bfloat16* W1bf    = (__hip_bfloat16*)(ws + OFF_W1BF);
    __hip_bfloat16* W2bf    = (__hip_bfloat16*)(ws + OFF_W2BF);
    int*            ebuf    = (int*)(ws + OFF_EBUF);
    int*            staging = (int*)(ws + OFF_STAGE);          // aliases h1s/r1
    __hip_bfloat16* h1s     = (__hip_bfloat16*)(ws + OFF_H1);  // h2s reuses
    __hip_bfloat16* r1      = (__hip_bfloat16*)(ws + OFF_R1);

    // --- weights to bf16 + zero bucket cursors ---
    k_cvtw<<<(NH * NF + NC * NH + 255) / 256, 256, 0, stream>>>(W1, W2, W1bf, W2bf, gcur);

    // --- CSR build: two-level bucket sort (staging aliases h1s/r1, dead here) ---
    k_binA<<<ABLK, 256, 0, stream>>>(srcp, dstp, gcur, staging);
    k_binB<<<NBUCK, 256, 0, stream>>>(gcur, staging, rowptr, dinv, ebuf);

    const int gemm_blocks = (NN + 255) / 256;   // 4 waves/block, 64 rows/wave
    const int node_blocks = (NN + 3) / 4;       // 4 waves/block, 1 node/wave

    // --- layer 1 ---
    k_gemm1<<<gemm_blocks, 256, 0, stream>>>(x, W1bf, dinv, h1s);
    k_gather1<<<node_blocks, 256, 0, stream>>>(rowptr, ebuf, dinv, h1s, b1, r1);

    // --- layer 2 (h2s reuses h1s's buffer, rows padded to 64) ---
    __hip_bfloat16* h2s = h1s;
    k_gemm2<<<gemm_blocks, 256, 0, stream>>>(r1, W2bf, dinv, h2s);
    k_gather2<<<node_blocks, 256, 0, stream>>>(rowptr, ebuf, dinv, h2s, b2,
                                               (float*)d_out);
}